// Round 7
// baseline (372.151 us; speedup 1.0000x reference)
//
#include <hip/hip_runtime.h>
#include <float.h>

typedef _Float16 half8 __attribute__((ext_vector_type(8)));
typedef float f32x4 __attribute__((ext_vector_type(4)));

#define NROWS 32768
#define D 64
#define K 1024
#define L 4
#define BROWS 32   /* rows per block: 1024 blocks = 4 blocks/CU = 100% occ */
#define PAD 68     /* resid LDS row stride in floats */

// ---------------------------------------------------------------------------
// Prep: from emb [D,K,L] fp32 build, per layer l:
//   embT  fp32 [L][K][D]  (exact codes for residual update)
//   ee    fp32 [L][K]     (||e||^2)
//   cbh   f16  [L][K][D]  (hi part)
//   cbl2  f16  [L][K][D]  (lo part * 4096 -- keeps lo in f16 normal range)
// ---------------------------------------------------------------------------
__global__ __launch_bounds__(64) void rvq_prep(const float* __restrict__ emb,
                                               float* __restrict__ embT,
                                               float* __restrict__ ee,
                                               _Float16* __restrict__ cbh,
                                               _Float16* __restrict__ cbl2) {
    const int kl = blockIdx.x * 64 + threadIdx.x;  // kl = k*4 + l
    const int l = kl & 3;
    const int k = kl >> 2;
    alignas(16) float v[D];
    alignas(16) _Float16 h[D];
    alignas(16) _Float16 lo[D];
    float s = 0.f;
#pragma unroll
    for (int d = 0; d < D; ++d) {
        float e = emb[d * (K * L) + kl];  // lane-coalesced over kl
        v[d] = e;
        s = fmaf(e, e, s);
    }
#pragma unroll
    for (int d = 0; d < D; ++d) {
        _Float16 hh = (_Float16)v[d];
        h[d] = hh;
        lo[d] = (_Float16)((v[d] - (float)hh) * 4096.f);
    }
    float4* dT = (float4*)(embT + ((size_t)l * K + k) * D);
#pragma unroll
    for (int j = 0; j < D / 4; ++j) dT[j] = ((const float4*)v)[j];
    float4* dH = (float4*)(cbh + ((size_t)l * K + k) * D);
    float4* dL = (float4*)(cbl2 + ((size_t)l * K + k) * D);
#pragma unroll
    for (int j = 0; j < D / 8; ++j) {  // 64 halfs = 8 float4
        dH[j] = ((const float4*)h)[j];
        dL[j] = ((const float4*)lo)[j];
    }
    ee[l * K + k] = s;
}

// ---------------------------------------------------------------------------
// Main: block = 32 rows, 8 waves = 2 row-groups (mg, 16 rows) x 4 code-groups
// (ng, 256 codes).  1024 blocks -> 4 blocks/CU, 32 waves/CU (100% occupancy,
// the round-4 fix: latency-bound at 43% occ / 14% MfmaUtil).  Per layer a
// wave computes S[16 x 256] via mfma_f32_16x16x32_f16 3-term f16 split;
// fp32 dist = (rr+ee) - 2*dot epilogue mirrors the reference's rounding
// (dist ~64 => 7.6e-6 comparison grid absorbs ~1e-7 split error).
// Residual master fp32 in LDS; updates exact fp32.
// ---------------------------------------------------------------------------
__global__ __launch_bounds__(512, 8) void rvq_main(const float* __restrict__ x,
                                                   const float* __restrict__ embT,
                                                   const float* __restrict__ ee,
                                                   const _Float16* __restrict__ cbh,
                                                   const _Float16* __restrict__ cbl2,
                                                   float* __restrict__ out) {
    __shared__ float s_res[BROWS * PAD];  // 8704 B
    __shared__ float s_rr[BROWS];
    __shared__ float s_ee[K];             // 4 KB, current layer
    __shared__ float s_bd[4][BROWS];
    __shared__ int s_bi[4][BROWS];
    __shared__ int s_widx[BROWS];

    const int tid = threadIdx.x;
    const int lane = tid & 63;
    const int wave = tid >> 6;
    const int mg = wave >> 2;  // 0..1  row group (16 rows)
    const int ng = wave & 3;   // 0..3  code group (256 codes)
    const int c0 = lane & 15;  // MFMA col class / A row
    const int g4 = lane >> 4;  // MFMA k-group / row-subgroup

    const int rowbase = blockIdx.x * BROWS;
    const int urow = tid >> 4;        // update/IO: row 0..31 (16 thr/row)
    const int ud0 = (tid & 15) * 4;   // update/IO: dim base (one float4)

    // ---- init: x -> s_res, fused rr ----
    {
        const float4* xp = (const float4*)(x + (size_t)(rowbase + urow) * D + ud0);
        float4 a = xp[0];
        ((float4*)(s_res + urow * PAD + ud0))[0] = a;
        float ss = a.x * a.x;
        ss = fmaf(a.y, a.y, ss); ss = fmaf(a.z, a.z, ss); ss = fmaf(a.w, a.w, ss);
        ss += __shfl_xor(ss, 1);
        ss += __shfl_xor(ss, 2);
        ss += __shfl_xor(ss, 4);
        ss += __shfl_xor(ss, 8);
        if ((tid & 15) == 0) s_rr[urow] = ss;
    }

    for (int l = 0; l < L; ++l) {
        __syncthreads();  // resid+rr ready; prior epilogue done with s_ee
        s_ee[tid] = ee[l * K + tid];
        s_ee[tid + 512] = ee[l * K + tid + 512];
        __syncthreads();

        // per-lane rr for the 4 acc rows this lane covers
        float rrv[4];
#pragma unroll
        for (int j = 0; j < 4; ++j) rrv[j] = s_rr[mg * 16 + g4 * 4 + j];

        // A fragments (residual rows), f16 hi/lo.  A[16x32]: lane row = c0,
        // k = g4*8..+7 within each 32-wide k-step.
        half8 Ah[2], Al[2];  // [kstep]
#pragma unroll
        for (int ks = 0; ks < 2; ++ks) {
            const float* src = s_res + (mg * 16 + c0) * PAD + ks * 32 + g4 * 8;
            float4 p = ((const float4*)src)[0];
            float4 q = ((const float4*)src)[1];
            float vv[8] = {p.x, p.y, p.z, p.w, q.x, q.y, q.z, q.w};
            half8 hh, ll;
#pragma unroll
            for (int e = 0; e < 8; ++e) {
                _Float16 t = (_Float16)vv[e];
                hh[e] = t;
                ll[e] = (_Float16)(vv[e] - (float)t);
            }
            Ah[ks] = hh;
            Al[ks] = ll;
        }

        float best[4];
        int bidx[4];
#pragma unroll
        for (int j = 0; j < 4; ++j) { best[j] = FLT_MAX; bidx[j] = 0; }

        const _Float16* cbhL = cbh + (size_t)l * K * D;
        const _Float16* cblL = cbl2 + (size_t)l * K * D;

#pragma unroll 1
        for (int ch = 0; ch < 8; ++ch) {
            const int cb0 = ng * 256 + ch * 32;
            f32x4 accA[2], accB[2];  // [nt]
#pragma unroll
            for (int nt = 0; nt < 2; ++nt) {
                accA[nt] = (f32x4){0.f, 0.f, 0.f, 0.f};
                accB[nt] = (f32x4){0.f, 0.f, 0.f, 0.f};
            }
#pragma unroll
            for (int nt = 0; nt < 2; ++nt) {
                const size_t ob = (size_t)(cb0 + nt * 16 + c0) * D + g4 * 8;
                half8 bh0 = *(const half8*)(cbhL + ob);
                half8 bh1 = *(const half8*)(cbhL + ob + 32);
                half8 bl0 = *(const half8*)(cblL + ob);
                half8 bl1 = *(const half8*)(cblL + ob + 32);
                f32x4 a = accA[nt], b = accB[nt];
                a = __builtin_amdgcn_mfma_f32_16x16x32_f16(Ah[0], bh0, a, 0, 0, 0);
                a = __builtin_amdgcn_mfma_f32_16x16x32_f16(Al[0], bh0, a, 0, 0, 0);
                b = __builtin_amdgcn_mfma_f32_16x16x32_f16(Ah[0], bl0, b, 0, 0, 0);
                a = __builtin_amdgcn_mfma_f32_16x16x32_f16(Ah[1], bh1, a, 0, 0, 0);
                a = __builtin_amdgcn_mfma_f32_16x16x32_f16(Al[1], bh1, a, 0, 0, 0);
                b = __builtin_amdgcn_mfma_f32_16x16x32_f16(Ah[1], bl1, b, 0, 0, 0);
                accA[nt] = a;
                accB[nt] = b;
            }
            // epilogue: dist = (rr+ee) - 2*(accA + accB*2^-12); running argmin
#pragma unroll
            for (int nt = 0; nt < 2; ++nt) {
                float eev = s_ee[cb0 + nt * 16 + c0];
                int idv = cb0 + nt * 16 + c0;
#pragma unroll
                for (int j = 0; j < 4; ++j) {
                    float t = rrv[j] + eev;
                    float sd = fmaf(accB[nt][j], 2.44140625e-4f, accA[nt][j]);
                    float dd = fmaf(-2.f, sd, t);
                    bool c = dd < best[j];  // ascending codes: strict < = first idx
                    best[j] = c ? dd : best[j];
                    bidx[j] = c ? idv : bidx[j];
                }
            }
        }

        // intra-wave argmin across the 16 col-classes (per row), idx tie-break
#pragma unroll
        for (int j = 0; j < 4; ++j) {
            float d1 = best[j];
            int i1 = bidx[j];
#pragma unroll
            for (int m = 1; m <= 8; m <<= 1) {
                float d2 = __shfl_xor(d1, m);
                int i2 = __shfl_xor(i1, m);
                if (d2 < d1 || (d2 == d1 && i2 < i1)) { d1 = d2; i1 = i2; }
            }
            if (c0 == 0) {
                int row = mg * 16 + g4 * 4 + j;
                s_bd[ng][row] = d1;
                s_bi[ng][row] = i1;
            }
        }
        __syncthreads();
        if (tid < BROWS) {
            float gb = s_bd[0][tid];
            int gi = s_bi[0][tid];
#pragma unroll
            for (int n = 1; n < 4; ++n) {
                float dn = s_bd[n][tid];  // ng ascending = code ranges ascending
                int in = s_bi[n][tid];
                if (dn < gb) { gb = dn; gi = in; }
            }
            s_widx[tid] = gi;
        }
        __syncthreads();

        // residual update (exact fp32) + fused rr for next layer
        {
            const int w = s_widx[urow];
            const float4 u = *(const float4*)(embT + ((size_t)l * K + w) * D + ud0);
            float* rp = s_res + urow * PAD + ud0;
            float4 r0 = ((float4*)rp)[0];
            r0.x -= u.x; r0.y -= u.y; r0.z -= u.z; r0.w -= u.w;
            ((float4*)rp)[0] = r0;
            float ss = r0.x * r0.x;
            ss = fmaf(r0.y, r0.y, ss); ss = fmaf(r0.z, r0.z, ss); ss = fmaf(r0.w, r0.w, ss);
            ss += __shfl_xor(ss, 1);
            ss += __shfl_xor(ss, 2);
            ss += __shfl_xor(ss, 4);
            ss += __shfl_xor(ss, 8);
            if ((tid & 15) == 0) s_rr[urow] = ss;
        }
    }

    // out = x - residual_final (same thread wrote these s_res bytes: no barrier)
    {
        const float4 a = *(const float4*)(x + (size_t)(rowbase + urow) * D + ud0);
        const float4 r0 = *(const float4*)(s_res + urow * PAD + ud0);
        float4 o0;
        o0.x = a.x - r0.x; o0.y = a.y - r0.y; o0.z = a.z - r0.z; o0.w = a.w - r0.w;
        *(float4*)(out + (size_t)(rowbase + urow) * D + ud0) = o0;
    }
}

extern "C" void kernel_launch(void* const* d_in, const int* in_sizes, int n_in,
                              void* d_out, int out_size, void* d_ws, size_t ws_size,
                              hipStream_t stream) {
    const float* x = (const float*)d_in[0];    // [32,32,32,64] fp32
    const float* emb = (const float*)d_in[1];  // [64,1024,4] fp32
    float* out = (float*)d_out;

    char* ws = (char*)d_ws;
    float* embT = (float*)ws;                                  // 1 MB
    float* ee = (float*)(ws + (size_t)L * K * D * 4);          // 16 KB
    _Float16* cbh = (_Float16*)(ws + (size_t)L * K * D * 4 + L * K * 4);
    _Float16* cbl2 = (_Float16*)(ws + (size_t)L * K * D * 4 + L * K * 4 + (size_t)L * K * D * 2);

    rvq_prep<<<(K * L) / 64, 64, 0, stream>>>(emb, embT, ee, cbh, cbl2);
    rvq_main<<<NROWS / BROWS, 512, 0, stream>>>(x, embT, ee, cbh, cbl2, out);
}

// Round 10
// 193.239 us; speedup vs baseline: 1.9259x; 1.9259x over previous
//
#include <hip/hip_runtime.h>
#include <float.h>

typedef _Float16 half8 __attribute__((ext_vector_type(8)));
typedef float f32x4 __attribute__((ext_vector_type(4)));

#define NROWS 32768
#define D 64
#define K 1024
#define L 4
#define BROWS 64   /* rows/block: 512 blocks = 2/CU -- the L2-friendly shape (18MB fetch) */
#define PAD 68     /* resid LDS row stride in floats */

// ---------------------------------------------------------------------------
// Prep: from emb [D,K,L] fp32 build, per layer l:
//   embT  fp32 [L][K][D]  (exact codes for residual update)
//   ee    fp32 [L][K]     (||e||^2)
//   cbh   f16  [L][K][D]  (hi part)
//   cbl2  f16  [L][K][D]  (lo part * 4096 -- keeps lo in f16 normal range)
// ---------------------------------------------------------------------------
__global__ __launch_bounds__(64) void rvq_prep(const float* __restrict__ emb,
                                               float* __restrict__ embT,
                                               float* __restrict__ ee,
                                               _Float16* __restrict__ cbh,
                                               _Float16* __restrict__ cbl2) {
    const int kl = blockIdx.x * 64 + threadIdx.x;  // kl = k*4 + l
    const int l = kl & 3;
    const int k = kl >> 2;
    alignas(16) float v[D];
    alignas(16) _Float16 h[D];
    alignas(16) _Float16 lo[D];
    float s = 0.f;
#pragma unroll
    for (int d = 0; d < D; ++d) {
        float e = emb[d * (K * L) + kl];  // lane-coalesced over kl
        v[d] = e;
        s = fmaf(e, e, s);
    }
#pragma unroll
    for (int d = 0; d < D; ++d) {
        _Float16 hh = (_Float16)v[d];
        h[d] = hh;
        lo[d] = (_Float16)((v[d] - (float)hh) * 4096.f);
    }
    float4* dT = (float4*)(embT + ((size_t)l * K + k) * D);
#pragma unroll
    for (int j = 0; j < D / 4; ++j) dT[j] = ((const float4*)v)[j];
    float4* dH = (float4*)(cbh + ((size_t)l * K + k) * D);
    float4* dL = (float4*)(cbl2 + ((size_t)l * K + k) * D);
#pragma unroll
    for (int j = 0; j < D / 8; ++j) {  // 64 halfs = 8 float4
        dH[j] = ((const float4*)h)[j];
        dL[j] = ((const float4*)lo)[j];
    }
    ee[l * K + k] = s;
}

// ---------------------------------------------------------------------------
// Main: block = 64 rows, 8 waves = 2 row-groups (mg, 32 rows) x 4 code-groups
// (ng, 256 codes).  BROWS=32/100%-occ variant REGRESSED (145->326us, FETCH
// 18->114MB: L2 thrash); this keeps the L2-friendly 512-block shape and hides
// B-load latency with a 1-step register-prefetch pipeline (16-code steps,
// ping-pong named buffers, counted-vmcnt style).  Per step: 12 MFMA
// (mfma_f32_16x16x32_f16, 3-term f16 split) + fp32 argmin epilogue.
// Candidate order per row identical to previous passing kernels -> absmax
// must remain 9.765625e-4.
// ---------------------------------------------------------------------------
__global__ __launch_bounds__(512, 4) void rvq_main(const float* __restrict__ x,
                                                   const float* __restrict__ embT,
                                                   const float* __restrict__ ee,
                                                   const _Float16* __restrict__ cbh,
                                                   const _Float16* __restrict__ cbl2,
                                                   float* __restrict__ out) {
    __shared__ float s_res[BROWS * PAD];  // 17408 B
    __shared__ float s_rr[BROWS];
    __shared__ float s_ee[K];             // 4 KB, current layer
    __shared__ float s_bd[4][BROWS];
    __shared__ int s_bi[4][BROWS];
    __shared__ int s_widx[BROWS];

    const int tid = threadIdx.x;
    const int lane = tid & 63;
    const int wave = tid >> 6;
    const int mg = wave >> 2;  // 0..1  row group (32 rows)
    const int ng = wave & 3;   // 0..3  code group (256 codes = 16 steps of 16)
    const int c0 = lane & 15;  // MFMA col class / A row
    const int g4 = lane >> 4;  // MFMA k-group / row-subgroup

    const int rowbase = blockIdx.x * BROWS;
    const int urow = tid >> 3;        // update/IO: row 0..63 (8 thr/row)
    const int ud0 = (tid & 7) * 8;    // update/IO: dim base (two float4)

    // ---- init: x -> s_res, fused rr ----
    {
        const float4* xp = (const float4*)(x + (size_t)(rowbase + urow) * D + ud0);
        float4 a = xp[0], b = xp[1];
        float* dst = s_res + urow * PAD + ud0;
        ((float4*)dst)[0] = a;
        ((float4*)dst)[1] = b;
        float ss = a.x * a.x;
        ss = fmaf(a.y, a.y, ss); ss = fmaf(a.z, a.z, ss); ss = fmaf(a.w, a.w, ss);
        ss = fmaf(b.x, b.x, ss); ss = fmaf(b.y, b.y, ss); ss = fmaf(b.z, b.z, ss);
        ss = fmaf(b.w, b.w, ss);
        ss += __shfl_xor(ss, 1);
        ss += __shfl_xor(ss, 2);
        ss += __shfl_xor(ss, 4);
        if ((tid & 7) == 0) s_rr[urow] = ss;
    }

// prefetch loads for 16-code step S of this wave's slice
#define LOADB(S, BH0, BH1, BL0, BL1)                              \
    do {                                                          \
        const int cb16_ = ng * 256 + (S)*16;                      \
        const size_t ob_ = (size_t)(cb16_ + c0) * D + g4 * 8;     \
        BH0 = *(const half8*)(cbhL + ob_);                        \
        BH1 = *(const half8*)(cbhL + ob_ + 32);                   \
        BL0 = *(const half8*)(cblL + ob_);                        \
        BL1 = *(const half8*)(cblL + ob_ + 32);                   \
    } while (0)

// compute + argmin for step S using fragments (order matches prior rounds)
#define COMP(S, BH0, BH1, BL0, BL1)                                              \
    do {                                                                         \
        const int cb16_ = ng * 256 + (S)*16;                                     \
        const float eev_ = s_ee[cb16_ + c0];                                     \
        const int idv_ = cb16_ + c0;                                             \
        _Pragma("unroll") for (int mt = 0; mt < 2; ++mt) {                       \
            f32x4 a_ = (f32x4){0.f, 0.f, 0.f, 0.f};                              \
            f32x4 b_ = (f32x4){0.f, 0.f, 0.f, 0.f};                              \
            a_ = __builtin_amdgcn_mfma_f32_16x16x32_f16(Ah[mt][0], BH0, a_, 0, 0, 0); \
            a_ = __builtin_amdgcn_mfma_f32_16x16x32_f16(Al[mt][0], BH0, a_, 0, 0, 0); \
            b_ = __builtin_amdgcn_mfma_f32_16x16x32_f16(Ah[mt][0], BL0, b_, 0, 0, 0); \
            a_ = __builtin_amdgcn_mfma_f32_16x16x32_f16(Ah[mt][1], BH1, a_, 0, 0, 0); \
            a_ = __builtin_amdgcn_mfma_f32_16x16x32_f16(Al[mt][1], BH1, a_, 0, 0, 0); \
            b_ = __builtin_amdgcn_mfma_f32_16x16x32_f16(Ah[mt][1], BL1, b_, 0, 0, 0); \
            _Pragma("unroll") for (int j = 0; j < 4; ++j) {                      \
                float t_ = rrv[mt][j] + eev_;                                    \
                float sd_ = fmaf(b_[j], 2.44140625e-4f, a_[j]);                  \
                float dd_ = fmaf(-2.f, sd_, t_);                                 \
                bool c_ = dd_ < best[mt][j];                                     \
                best[mt][j] = c_ ? dd_ : best[mt][j];                            \
                bidx[mt][j] = c_ ? idv_ : bidx[mt][j];                           \
            }                                                                    \
        }                                                                        \
    } while (0)

    for (int l = 0; l < L; ++l) {
        __syncthreads();  // resid+rr ready; prior epilogue done with s_ee
        s_ee[tid] = ee[l * K + tid];
        s_ee[tid + 512] = ee[l * K + tid + 512];
        __syncthreads();

        // per-lane rr for the 8 (mt,j) rows this lane's accs cover
        float rrv[2][4];
#pragma unroll
        for (int mt = 0; mt < 2; ++mt)
#pragma unroll
            for (int j = 0; j < 4; ++j)
                rrv[mt][j] = s_rr[mg * 32 + mt * 16 + g4 * 4 + j];

        // A fragments (residual rows), f16 hi/lo
        half8 Ah[2][2], Al[2][2];  // [mt][kstep]
#pragma unroll
        for (int mt = 0; mt < 2; ++mt)
#pragma unroll
            for (int ks = 0; ks < 2; ++ks) {
                const float* src = s_res + (mg * 32 + mt * 16 + c0) * PAD + ks * 32 + g4 * 8;
                float4 p = ((const float4*)src)[0];
                float4 q = ((const float4*)src)[1];
                float vv[8] = {p.x, p.y, p.z, p.w, q.x, q.y, q.z, q.w};
                half8 hh, ll;
#pragma unroll
                for (int e = 0; e < 8; ++e) {
                    _Float16 t = (_Float16)vv[e];
                    hh[e] = t;
                    ll[e] = (_Float16)(vv[e] - (float)t);
                }
                Ah[mt][ks] = hh;
                Al[mt][ks] = ll;
            }

        float best[2][4];
        int bidx[2][4];
#pragma unroll
        for (int mt = 0; mt < 2; ++mt)
#pragma unroll
            for (int j = 0; j < 4; ++j) { best[mt][j] = FLT_MAX; bidx[mt][j] = 0; }

        const _Float16* cbhL = cbh + (size_t)l * K * D;
        const _Float16* cblL = cbl2 + (size_t)l * K * D;

        // --- 16-step software pipeline, ping-pong register buffers ---
        half8 pA_h0, pA_h1, pA_l0, pA_l1;  // buffer A
        half8 pB_h0, pB_h1, pB_l0, pB_l1;  // buffer B
        LOADB(0, pA_h0, pA_h1, pA_l0, pA_l1);
#pragma unroll 1
        for (int sp = 0; sp < 8; ++sp) {
            const int s0 = sp * 2;
            LOADB(s0 + 1, pB_h0, pB_h1, pB_l0, pB_l1);   // prefetch odd step
            COMP(s0, pA_h0, pA_h1, pA_l0, pA_l1);        // compute even step
            const int s2 = (s0 + 2 < 16) ? s0 + 2 : 0;   // tail: redundant, unused
            LOADB(s2, pA_h0, pA_h1, pA_l0, pA_l1);       // prefetch next even
            COMP(s0 + 1, pB_h0, pB_h1, pB_l0, pB_l1);    // compute odd step
        }

        // intra-wave argmin across the 16 col-classes (per row), idx tie-break
#pragma unroll
        for (int mt = 0; mt < 2; ++mt)
#pragma unroll
            for (int j = 0; j < 4; ++j) {
                float d1 = best[mt][j];
                int i1 = bidx[mt][j];
#pragma unroll
                for (int m = 1; m <= 8; m <<= 1) {
                    float d2 = __shfl_xor(d1, m);
                    int i2 = __shfl_xor(i1, m);
                    if (d2 < d1 || (d2 == d1 && i2 < i1)) { d1 = d2; i1 = i2; }
                }
                if (c0 == 0) {
                    int row = mg * 32 + mt * 16 + g4 * 4 + j;
                    s_bd[ng][row] = d1;
                    s_bi[ng][row] = i1;
                }
            }
        __syncthreads();
        if (tid < BROWS) {
            float gb = s_bd[0][tid];
            int gi = s_bi[0][tid];
#pragma unroll
            for (int n = 1; n < 4; ++n) {
                float dn = s_bd[n][tid];  // ng ascending = code ranges ascending
                int in = s_bi[n][tid];
                if (dn < gb) { gb = dn; gi = in; }
            }
            s_widx[tid] = gi;
        }
        __syncthreads();

        // residual update (exact fp32) + fused rr for next layer
        {
            const int w = s_widx[urow];
            const float* up = embT + ((size_t)l * K + w) * D + ud0;
            float4 u0 = ((const float4*)up)[0];
            float4 u1 = ((const float4*)up)[1];
            float* rp = s_res + urow * PAD + ud0;
            float4 r0 = ((float4*)rp)[0];
            float4 r1 = ((float4*)rp)[1];
            r0.x -= u0.x; r0.y -= u0.y; r0.z -= u0.z; r0.w -= u0.w;
            r1.x -= u1.x; r1.y -= u1.y; r1.z -= u1.z; r1.w -= u1.w;
            ((float4*)rp)[0] = r0;
            ((float4*)rp)[1] = r1;
            float ss = r0.x * r0.x;
            ss = fmaf(r0.y, r0.y, ss); ss = fmaf(r0.z, r0.z, ss); ss = fmaf(r0.w, r0.w, ss);
            ss = fmaf(r1.x, r1.x, ss); ss = fmaf(r1.y, r1.y, ss); ss = fmaf(r1.z, r1.z, ss);
            ss = fmaf(r1.w, r1.w, ss);
            ss += __shfl_xor(ss, 1);
            ss += __shfl_xor(ss, 2);
            ss += __shfl_xor(ss, 4);
            if ((tid & 7) == 0) s_rr[urow] = ss;
        }
    }

    // out = x - residual_final (same thread wrote these s_res bytes: no barrier)
    {
        const float4* xp = (const float4*)(x + (size_t)(rowbase + urow) * D + ud0);
        const float* rp = s_res + urow * PAD + ud0;
        float4 a = xp[0], b = xp[1];
        float4 r0 = ((const float4*)rp)[0];
        float4 r1 = ((const float4*)rp)[1];
        float4 o0, o1;
        o0.x = a.x - r0.x; o0.y = a.y - r0.y; o0.z = a.z - r0.z; o0.w = a.w - r0.w;
        o1.x = b.x - r1.x; o1.y = b.y - r1.y; o1.z = b.z - r1.z; o1.w = b.w - r1.w;
        float4* op = (float4*)(out + (size_t)(rowbase + urow) * D + ud0);
        op[0] = o0;
        op[1] = o1;
    }
#undef LOADB
#undef COMP
}

extern "C" void kernel_launch(void* const* d_in, const int* in_sizes, int n_in,
                              void* d_out, int out_size, void* d_ws, size_t ws_size,
                              hipStream_t stream) {
    const float* x = (const float*)d_in[0];    // [32,32,32,64] fp32
    const float* emb = (const float*)d_in[1];  // [64,1024,4] fp32
    float* out = (float*)d_out;

    char* ws = (char*)d_ws;
    float* embT = (float*)ws;                                  // 1 MB
    float* ee = (float*)(ws + (size_t)L * K * D * 4);          // 16 KB
    _Float16* cbh = (_Float16*)(ws + (size_t)L * K * D * 4 + L * K * 4);
    _Float16* cbl2 = (_Float16*)(ws + (size_t)L * K * D * 4 + L * K * 4 + (size_t)L * K * D * 2);

    rvq_prep<<<(K * L) / 64, 64, 0, stream>>>(emb, embT, ee, cbh, cbl2);
    rvq_main<<<NROWS / BROWS, 512, 0, stream>>>(x, embT, ee, cbh, cbl2, out);
}